// Round 5
// baseline (201.335 us; speedup 1.0000x reference)
//
#include <hip/hip_runtime.h>
#include <math.h>
#include <stdint.h>

#define B_    8
#define N_    3136
#define DIM_  147
#define KP_   160
#define TOK_  (B_*N_)      // 25088
#define QKV3_ 192

typedef __attribute__((ext_vector_type(4))) float f32x4;
typedef __attribute__((ext_vector_type(4))) unsigned int u32x4;
typedef __attribute__((ext_vector_type(8))) short short8;
typedef union { short8 s; u32x4 u; } pk8;

static __device__ __forceinline__ unsigned short f2b(float f){
  unsigned int u = __float_as_uint(f);
  u += 0x7fffu + ((u>>16)&1u);          // RNE
  return (unsigned short)(u>>16);
}
static __device__ __forceinline__ unsigned int pk2(float a, float b){   // RNE pack
  return ((unsigned int)f2b(b)<<16) | (unsigned int)f2b(a);
}
static __device__ __forceinline__ unsigned int pk2t(float a, float b){  // trunc pack (P only)
  return (__float_as_uint(b) & 0xffff0000u) | (__float_as_uint(a)>>16);
}
static __device__ __forceinline__ float b2f(unsigned short s){
  return __uint_as_float(((unsigned int)s)<<16);
}

// ---------------------------------------------------------------- K0: pack weights -> bf16
__global__ __launch_bounds__(256) void k_prep(const float* __restrict__ qkvw,
                                              const float* __restrict__ projw,
                                              const float* __restrict__ fc1w,
                                              const float* __restrict__ fc2w,
                                              unsigned short* __restrict__ wp,
                                              unsigned short* __restrict__ wpj,
                                              unsigned short* __restrict__ w1b,
                                              unsigned short* __restrict__ w2b){
  int idx = blockIdx.x*256 + threadIdx.x;
  if(idx < QKV3_*KP_){
    int n = idx / KP_, k = idx - n*KP_;
    wp[idx] = f2b((k < DIM_) ? qkvw[n*DIM_ + k] : 0.f);
  }
  if(idx < 4096){
    wpj[idx] = f2b(projw[idx]);
    w1b[idx] = f2b(fc1w[idx]);
    w2b[idx] = f2b(fc2w[idx]);
  }
}

// ---------------------------------------------------------------- K1: fused LN1 + QKV GEMM
__global__ __launch_bounds__(256,2) void k_qkv(const float* __restrict__ x,
                                               const float* __restrict__ w1,
                                               const float* __restrict__ b1,
                                               const unsigned short* __restrict__ wp,
                                               const float* __restrict__ scale,
                                               unsigned short* __restrict__ qb,
                                               unsigned short* __restrict__ kb,
                                               unsigned short* __restrict__ vtb,
                                               unsigned short* __restrict__ vfb){
  __shared__ alignas(16) unsigned short A_[32*168];  // 10752 B
  __shared__ alignas(16) unsigned short VT[64*36];   //  4608 B
  int tid = threadIdx.x;
  int w = tid>>6, lane = tid&63, quad = lane>>4, l16 = lane&15;
  int t0 = blockIdx.x*32;
  float sc2 = scale[0] * 1.44269504089f;

  // LN1: 8 threads per token, x held in registers
  {
    int g = tid>>3, e = tid&7;
    const float* xr = x + (size_t)(t0+g)*147;
    float xv[19];
    float s = 0.f, sq = 0.f;
    #pragma unroll
    for(int i=0;i<19;i++){
      int col = e + 8*i;
      float v = (col < 147) ? xr[col] : 0.f;
      xv[i] = v; s += v; sq += v*v;
    }
    s  += __shfl_xor(s,1,64);  s  += __shfl_xor(s,2,64);  s  += __shfl_xor(s,4,64);
    sq += __shfl_xor(sq,1,64); sq += __shfl_xor(sq,2,64); sq += __shfl_xor(sq,4,64);
    float mean = s*(1.f/147.f);
    float var  = sq*(1.f/147.f) - mean*mean;
    float rstd = rsqrtf(var + 1e-5f);
    #pragma unroll
    for(int i=0;i<19;i++){
      int col = e + 8*i;
      if(col < 147) A_[g*168 + col] = f2b((xv[i]-mean)*rstd*w1[col] + b1[col]);
    }
    #pragma unroll
    for(int i=0;i<2;i++){
      int col = 144 + e + 8*i;
      if(col >= 147 && col < 160) A_[g*168 + col] = 0;
    }
  }
  __syncthreads();
  int mh = (w&1)*16, cb = (w>>1)*96;
  short8 Af[5];
  #pragma unroll
  for(int kk=0;kk<5;kk++)
    Af[kk] = *(const short8*)(A_ + (mh+l16)*168 + kk*32 + quad*8);
  f32x4 acc[6];
  #pragma unroll
  for(int i=0;i<6;i++) acc[i] = (f32x4){0.f,0.f,0.f,0.f};
  #pragma unroll
  for(int nt=0;nt<6;nt++){
    #pragma unroll
    for(int kk=0;kk<5;kk++){
      short8 Bf = *(const short8*)(wp + (size_t)(cb+nt*16+l16)*160 + kk*32 + quad*8);
      acc[nt] = __builtin_amdgcn_mfma_f32_16x16x32_bf16(Af[kk], Bf, acc[nt], 0,0,0);
    }
  }
  #pragma unroll
  for(int nt=0;nt<6;nt++){
    int o = cb + nt*16 + l16;
    #pragma unroll
    for(int r=0;r<4;r++){
      int tl = mh + quad*4 + r;
      int mg = t0 + tl;
      float val = acc[nt][r];
      if(o < 64){
        qb[(size_t)mg*64 + o] = f2b(val*sc2);
      } else if(o < 128){
        kb[(size_t)mg*64 + (o-64)] = f2b(val);
      } else {
        int hd = o - 128;
        unsigned short vb = f2b(val);
        vfb[(size_t)mg*64 + hd] = vb;
        VT[hd*36 + tl] = vb;
      }
    }
  }
  __syncthreads();
  {
    int b = t0 / N_, n0 = t0 - b*N_;
    const unsigned int* VT32 = (const unsigned int*)VT;
    unsigned int* vg = (unsigned int*)vtb + ((size_t)b*64)*(N_/2) + (n0>>1);
    for(int rep=0;rep<4;rep++){
      int f = rep*256 + tid;
      int row = f>>4, c = f&15;
      vg[(size_t)row*(N_/2) + c] = VT32[row*18 + c];
    }
  }
}

// ---------------------------------------------------------------- K2: attention — register-resident, barrier-free
// grid (98,4,8), 64 thr (1 wave, 32 q rows). K/V fragments double-buffered in VGPRs,
// loaded directly from global (sigma row-perm folded into K addresses). LDS only for
// the wave-private O^T transpose at the epilogue (no __syncthreads anywhere).
__global__ __launch_bounds__(64,2) void k_attn(const unsigned short* __restrict__ qb,
                                               const unsigned short* __restrict__ kb,
                                               const unsigned short* __restrict__ vtb,
                                               unsigned short* __restrict__ Opart,
                                               float* __restrict__ lpart){
  __shared__ alignas(16) unsigned int L[32*36];   // 4608 B, wave-private epilogue scratch
  int lane = threadIdx.x & 63;
  int quad = lane>>4, l16 = lane&15;
  int qw = blockIdx.x, sp = blockIdx.y, b = blockIdx.z;
  int q0 = qw*32;
  int qt = qw>>1;                 // 64-wide kv tile containing the diagonal
  int kv0 = (sp*49)>>2, kv1 = ((sp+1)*49)>>2;

  // Q fragments (B-operand): n=l16 -> token q0+qs*16+l16, k=quad*8+j -> hd kk*32+quad*8
  short8 Qf[2][2];
  {
    const unsigned short* qg = qb + ((size_t)b*N_ + q0)*64;
    #pragma unroll
    for(int qs=0;qs<2;qs++)
      #pragma unroll
      for(int kk=0;kk<2;kk++)
        Qf[qs][kk] = *(const short8*)(qg + (qs*16+l16)*64 + kk*32 + quad*8);
  }
  // per-lane byte offsets into a kv tile
  int koff[4], voff[4];
  #pragma unroll
  for(int jt=0;jt<4;jt++){
    int p = jt*16 + l16;
    int sig = (p&32)|((p&12)<<1)|((p&16)>>2)|(p&3);   // K row permutation
    koff[jt] = sig*128 + quad*16;
    voff[jt] = ((jt*16 + l16)*N_ + quad*8)*2;
  }
  const char* kT = (const char*)kb + (size_t)b*N_*128 + (size_t)kv0*8192;
  const char* vT = (const char*)vtb + (size_t)b*64*(size_t)(N_*2) + (size_t)kv0*128;

  f32x4 O[2][4];
  #pragma unroll
  for(int qs=0;qs<2;qs++) for(int j=0;j<4;j++) O[qs][j] = (f32x4){0.f,0.f,0.f,0.f};
  float lr[2] = {0.f, 0.f};

  auto loadK = [&](short8* Kf, const char* base){
    #pragma unroll
    for(int jt=0;jt<4;jt++){
      Kf[jt*2]   = *(const short8*)(base + koff[jt]);
      Kf[jt*2+1] = *(const short8*)(base + koff[jt] + 64);
    }
  };
  auto loadV = [&](short8* Vf, const char* base){
    #pragma unroll
    for(int j=0;j<4;j++){
      Vf[j*2]   = *(const short8*)(base + voff[j]);
      Vf[j*2+1] = *(const short8*)(base + voff[j] + 64);
    }
  };
  auto tile = [&](const short8* Kf, const short8* Vf, int kvt){
    #pragma unroll
    for(int qs=0;qs<2;qs++){
      f32x4 S[4];
      #pragma unroll
      for(int jt=0;jt<4;jt++){
        f32x4 z = (f32x4){0.f,0.f,0.f,0.f};
        S[jt] = __builtin_amdgcn_mfma_f32_16x16x32_bf16(Kf[jt*2],   Qf[qs][0], z, 0,0,0);
        S[jt] = __builtin_amdgcn_mfma_f32_16x16x32_bf16(Kf[jt*2+1], Qf[qs][1], S[jt], 0,0,0);
      }
      // lane's S[jt][r] is kv = (jt>>1)*32 + (jt&1)*4 + quad*8 + r (sigma-permuted C-layout)
      float p[4][4];
      if(kvt == qt){                         // diagonal tile (block-uniform branch)
        int dl = q0 + qs*16 + l16 - kvt*64;
        #pragma unroll
        for(int jt=0;jt<4;jt++){
          int kvb = (jt>>1)*32 + (jt&1)*4 + quad*8;
          #pragma unroll
          for(int r=0;r<4;r++){
            float pv = (kvb + r == dl) ? 0.f : __builtin_amdgcn_exp2f(S[jt][r]);
            p[jt][r] = pv; lr[qs] += pv;
          }
        }
      } else {
        #pragma unroll
        for(int jt=0;jt<4;jt++)
          #pragma unroll
          for(int r=0;r<4;r++){
            float pv = __builtin_amdgcn_exp2f(S[jt][r]);
            p[jt][r] = pv; lr[qs] += pv;
          }
      }
      pk8 Pb0, Pb1;
      Pb0.u = (u32x4){ pk2t(p[0][0],p[0][1]), pk2t(p[0][2],p[0][3]),
                       pk2t(p[1][0],p[1][1]), pk2t(p[1][2],p[1][3]) };
      Pb1.u = (u32x4){ pk2t(p[2][0],p[2][1]), pk2t(p[2][2],p[2][3]),
                       pk2t(p[3][0],p[3][1]), pk2t(p[3][2],p[3][3]) };
      #pragma unroll
      for(int jt2=0;jt2<4;jt2++){
        O[qs][jt2] = __builtin_amdgcn_mfma_f32_16x16x32_bf16(Vf[jt2*2],   Pb0.s, O[qs][jt2], 0,0,0);
        O[qs][jt2] = __builtin_amdgcn_mfma_f32_16x16x32_bf16(Vf[jt2*2+1], Pb1.s, O[qs][jt2], 0,0,0);
      }
    }
  };

  // software-pipelined K-loop: loads for tile t+1 issued before computing tile t
  short8 K0[8], K1[8], V0[8], V1[8];
  loadK(K0, kT); loadV(V0, vT);
  int t = kv0;
  while(true){
    loadK(K1, kT + 8192); loadV(V1, vT + 128);   // prefetch t+1 (overrun at end is benign: stays in d_ws)
    tile(K0, V0, t);
    ++t; kT += 8192; vT += 128;
    if(t == kv1) break;
    loadK(K0, kT + 8192); loadV(V0, vT + 128);
    tile(K1, V1, t);
    ++t; kT += 8192; vT += 128;
    if(t == kv1) break;
  }

  // epilogue: reduce l across quads; wave-private LDS transpose O^T -> [q][hd]; coalesced store
  lr[0] += __shfl_xor(lr[0],16,64); lr[0] += __shfl_xor(lr[0],32,64);
  lr[1] += __shfl_xor(lr[1],16,64); lr[1] += __shfl_xor(lr[1],32,64);
  #pragma unroll
  for(int qs=0;qs<2;qs++){
    int q = qs*16 + l16;
    #pragma unroll
    for(int jt2=0;jt2<4;jt2++){
      L[q*36 + jt2*8 + quad*2]     = pk2(O[qs][jt2][0], O[qs][jt2][1]);
      L[q*36 + jt2*8 + quad*2 + 1] = pk2(O[qs][jt2][2], O[qs][jt2][3]);
    }
  }
  if(quad == 0){
    size_t lbase = (size_t)sp*TOK_ + (size_t)b*N_ + q0;
    lpart[lbase + l16]      = lr[0];
    lpart[lbase + 16 + l16] = lr[1];
  }
  {
    unsigned int* og = (unsigned int*)(Opart + ((size_t)sp*TOK_ + (size_t)b*N_ + q0)*64);
    #pragma unroll
    for(int rep=0;rep<4;rep++){
      int f = rep*64 + lane;          // 256 x4-units = 32 rows x 8
      int row = f>>3, c = f&7;
      *(u32x4*)(og + row*32 + c*4) = *(const u32x4*)&L[row*36 + c*4];
    }
  }
}

// ---------------------------------------------------------------- K3: merge + proj + residual(v) + LN2 + MLP + residual
__global__ __launch_bounds__(128) void k_mlp(const unsigned short* __restrict__ Opart,
                                             const float* __restrict__ lpart,
                                             const unsigned short* __restrict__ vfb,
                                             const unsigned short* __restrict__ wpj,
                                             const unsigned short* __restrict__ w1b,
                                             const unsigned short* __restrict__ w2b,
                                             const float* __restrict__ projb,
                                             const float* __restrict__ n2w,
                                             const float* __restrict__ n2b,
                                             const float* __restrict__ fc1b,
                                             const float* __restrict__ fc2b,
                                             float* __restrict__ out){
  __shared__ alignas(16) unsigned short Xs[32*72];   // 4608 B
  unsigned int* Xs32 = (unsigned int*)Xs;
  int tid = threadIdx.x;
  int w = tid>>6, lane = tid&63, quad = lane>>4, l16 = lane&15;
  int t0 = blockIdx.x*32;

  #pragma unroll
  for(int i=0;i<2;i++){
    int f = i*128 + tid;
    int row = f>>3, c = f&7;
    float lo[4] = {0,0,0,0}, hi[4] = {0,0,0,0};
    float lsum = 0.f;
    #pragma unroll
    for(int s=0;s<4;s++){
      u32x4 a = *((const u32x4*)(Opart + ((size_t)s*TOK_ + t0)*64) + row*8 + c);
      #pragma unroll
      for(int k=0;k<4;k++){
        lo[k] += __uint_as_float(a[k]<<16);
        hi[k] += __uint_as_float(a[k] & 0xffff0000u);
      }
      lsum += lpart[(size_t)s*TOK_ + t0 + row];
    }
    float linv = 1.f/lsum;
    u32x4 o;
    #pragma unroll
    for(int k=0;k<4;k++) o[k] = pk2(lo[k]*linv, hi[k]*linv);
    *(u32x4*)&Xs32[row*36 + c*4] = o;
  }
  __syncthreads();

  short8 Af[2];
  #pragma unroll
  for(int kk=0;kk<2;kk++)
    Af[kk] = *(const short8*)(Xs + (w*16+l16)*72 + kk*32 + quad*8);
  f32x4 acc[4];
  #pragma unroll
  for(int i=0;i<4;i++) acc[i] = (f32x4){0.f,0.f,0.f,0.f};
  #pragma unroll
  for(int jt=0;jt<4;jt++)
    #pragma unroll
    for(int kk=0;kk<2;kk++){
      short8 Bf = *(const short8*)(wpj + (jt*16+l16)*64 + kk*32 + quad*8);
      acc[jt] = __builtin_amdgcn_mfma_f32_16x16x32_bf16(Af[kk], Bf, acc[jt], 0,0,0);
    }
  float xa[4][4];
  #pragma unroll
  for(int jt=0;jt<4;jt++){
    int col = jt*16 + l16;
    float pb = projb[col];
    #pragma unroll
    for(int r=0;r<4;r++){
      int tg = t0 + w*16 + quad*4 + r;
      xa[jt][r] = acc[jt][r] + pb + b2f(vfb[(size_t)tg*64 + col]);
    }
  }
  #pragma unroll
  for(int r=0;r<4;r++){
    float s = 0.f, sq = 0.f;
    #pragma unroll
    for(int jt=0;jt<4;jt++){ s += xa[jt][r]; sq += xa[jt][r]*xa[jt][r]; }
    s  += __shfl_xor(s,1,64);  s  += __shfl_xor(s,2,64);
    s  += __shfl_xor(s,4,64);  s  += __shfl_xor(s,8,64);
    sq += __shfl_xor(sq,1,64); sq += __shfl_xor(sq,2,64);
    sq += __shfl_xor(sq,4,64); sq += __shfl_xor(sq,8,64);
    float mu = s*(1.f/64.f);
    float var = sq*(1.f/64.f) - mu*mu;
    float rstd = rsqrtf(var + 1e-5f);
    #pragma unroll
    for(int jt=0;jt<4;jt++){
      int col = jt*16 + l16;
      Xs[(w*16+quad*4+r)*72 + col] = f2b((xa[jt][r]-mu)*rstd*n2w[col] + n2b[col]);
    }
  }
  #pragma unroll
  for(int kk=0;kk<2;kk++)
    Af[kk] = *(const short8*)(Xs + (w*16+l16)*72 + kk*32 + quad*8);
  f32x4 acc2[4];
  #pragma unroll
  for(int i=0;i<4;i++) acc2[i] = (f32x4){0.f,0.f,0.f,0.f};
  #pragma unroll
  for(int jt=0;jt<4;jt++)
    #pragma unroll
    for(int kk=0;kk<2;kk++){
      short8 Bf = *(const short8*)(w1b + (jt*16+l16)*64 + kk*32 + quad*8);
      acc2[jt] = __builtin_amdgcn_mfma_f32_16x16x32_bf16(Af[kk], Bf, acc2[jt], 0,0,0);
    }
  #pragma unroll
  for(int jt=0;jt<4;jt++){
    int col = jt*16 + l16;
    float fb = fc1b[col];
    #pragma unroll
    for(int r=0;r<4;r++){
      float g = acc2[jt][r] + fb;
      float z = g*0.70710678118f;
      float az = fabsf(z);
      float t = 1.f/(1.f + 0.3275911f*az);
      float poly = ((((1.061405429f*t - 1.453152027f)*t + 1.421413741f)*t - 0.284496736f)*t + 0.254829592f)*t;
      float er = 1.f - poly*__builtin_amdgcn_exp2f(-az*az*1.44269504089f);
      er = (z < 0.f) ? -er : er;
      Xs[(w*16+quad*4+r)*72 + col] = f2b(0.5f*g*(1.f + er));
    }
  }
  #pragma unroll
  for(int kk=0;kk<2;kk++)
    Af[kk] = *(const short8*)(Xs + (w*16+l16)*72 + kk*32 + quad*8);
  f32x4 acc3[4];
  #pragma unroll
  for(int i=0;i<4;i++) acc3[i] = (f32x4){0.f,0.f,0.f,0.f};
  #pragma unroll
  for(int jt=0;jt<4;jt++)
    #pragma unroll
    for(int kk=0;kk<2;kk++){
      short8 Bf = *(const short8*)(w2b + (jt*16+l16)*64 + kk*32 + quad*8);
      acc3[jt] = __builtin_amdgcn_mfma_f32_16x16x32_bf16(Af[kk], Bf, acc3[jt], 0,0,0);
    }
  #pragma unroll
  for(int jt=0;jt<4;jt++){
    int col = jt*16 + l16;
    float ob2 = fc2b[col];
    #pragma unroll
    for(int r=0;r<4;r++){
      int tg = t0 + w*16 + quad*4 + r;
      out[(size_t)tg*64 + col] = xa[jt][r] + acc3[jt][r] + ob2;
    }
  }
}

// ---------------------------------------------------------------- launch
extern "C" void kernel_launch(void* const* d_in, const int* in_sizes, int n_in,
                              void* d_out, int out_size, void* d_ws, size_t ws_size,
                              hipStream_t stream){
  const float* x     = (const float*)d_in[0];
  const float* n1w   = (const float*)d_in[1];
  const float* n1b   = (const float*)d_in[2];
  const float* qkvw  = (const float*)d_in[3];
  const float* scale = (const float*)d_in[4];
  const float* projw = (const float*)d_in[5];
  const float* projb = (const float*)d_in[6];
  const float* n2w   = (const float*)d_in[7];
  const float* n2b   = (const float*)d_in[8];
  const float* fc1w  = (const float*)d_in[9];
  const float* fc1b  = (const float*)d_in[10];
  const float* fc2w  = (const float*)d_in[11];
  const float* fc2b  = (const float*)d_in[12];

  char* base = (char*)d_ws;
  unsigned short* wp  = (unsigned short*)(base + 0);          //    61440
  unsigned short* wpj = (unsigned short*)(base + 61440);      //     8192
  unsigned short* w1b = (unsigned short*)(base + 69632);      //     8192
  unsigned short* w2b = (unsigned short*)(base + 77824);      //     8192
  unsigned short* qb  = (unsigned short*)(base + 86016);      //  3211264
  unsigned short* kb  = (unsigned short*)(base + 3297280);    //  3211264
  unsigned short* vtb = (unsigned short*)(base + 6508544);    //  3211264
  unsigned short* vfb = (unsigned short*)(base + 9719808);    //  3211264
  unsigned short* Op  = (unsigned short*)(base + 12931072);   // 12845056 (4 splits bf16)
  float*          lp  = (float*)(base + 25776128);            //   401408  -> total 26177536

  hipLaunchKernelGGL(k_prep, dim3(120),      dim3(256), 0, stream,
                     qkvw, projw, fc1w, fc2w, wp, wpj, w1b, w2b);
  hipLaunchKernelGGL(k_qkv,  dim3(TOK_/32),  dim3(256), 0, stream,
                     x, n1w, n1b, wp, scale, qb, kb, vtb, vfb);
  hipLaunchKernelGGL(k_attn, dim3(98,4,8),   dim3(64),  0, stream, qb, kb, vtb, Op, lp);
  hipLaunchKernelGGL(k_mlp,  dim3(TOK_/32),  dim3(128), 0, stream, Op, lp, vfb,
                     wpj, w1b, w2b, projb, n2w, n2b, fc1b, fc2b, (float*)d_out);
}

// Round 7
// 150.128 us; speedup vs baseline: 1.3411x; 1.3411x over previous
//
#include <hip/hip_runtime.h>
#include <math.h>
#include <stdint.h>

#define B_    8
#define N_    3136
#define DIM_  147
#define KP_   160
#define TOK_  (B_*N_)      // 25088
#define QKV3_ 192
#define NSPLIT 4

typedef __attribute__((ext_vector_type(4))) float f32x4;
typedef __attribute__((ext_vector_type(4))) unsigned int u32x4;
typedef __attribute__((ext_vector_type(8))) short short8;
typedef union { short8 s; u32x4 u; } pk8;

static __device__ __forceinline__ unsigned short f2b(float f){
  unsigned int u = __float_as_uint(f);
  u += 0x7fffu + ((u>>16)&1u);          // RNE
  return (unsigned short)(u>>16);
}
static __device__ __forceinline__ unsigned int pk2(float a, float b){   // RNE pack
  return ((unsigned int)f2b(b)<<16) | (unsigned int)f2b(a);
}
static __device__ __forceinline__ unsigned int pk2t(float a, float b){  // trunc pack (P only)
  return (__float_as_uint(b) & 0xffff0000u) | (__float_as_uint(a)>>16);
}
static __device__ __forceinline__ float b2f(unsigned short s){
  return __uint_as_float(((unsigned int)s)<<16);
}

// async global->LDS, 16 B per lane; LDS dest = uniform base + lane*16
#define GLD16(gp, lp) __builtin_amdgcn_global_load_lds( \
    reinterpret_cast<const uint32_t __attribute__((address_space(1)))*>(reinterpret_cast<uintptr_t>(gp)), \
    reinterpret_cast<uint32_t __attribute__((address_space(3)))*>(reinterpret_cast<uintptr_t>(lp)), \
    16, 0, 0)

// ---------------------------------------------------------------- K0: pack weights -> bf16
__global__ __launch_bounds__(256) void k_prep(const float* __restrict__ qkvw,
                                              const float* __restrict__ projw,
                                              const float* __restrict__ fc1w,
                                              const float* __restrict__ fc2w,
                                              unsigned short* __restrict__ wp,
                                              unsigned short* __restrict__ wpj,
                                              unsigned short* __restrict__ w1b,
                                              unsigned short* __restrict__ w2b){
  int idx = blockIdx.x*256 + threadIdx.x;
  if(idx < QKV3_*KP_){
    int n = idx / KP_, k = idx - n*KP_;
    wp[idx] = f2b((k < DIM_) ? qkvw[n*DIM_ + k] : 0.f);
  }
  if(idx < 4096){
    wpj[idx] = f2b(projw[idx]);
    w1b[idx] = f2b(fc1w[idx]);
    w2b[idx] = f2b(fc2w[idx]);
  }
}

// ---------------------------------------------------------------- K1: fused LN1 + QKV GEMM
__global__ __launch_bounds__(256,2) void k_qkv(const float* __restrict__ x,
                                               const float* __restrict__ w1,
                                               const float* __restrict__ b1,
                                               const unsigned short* __restrict__ wp,
                                               const float* __restrict__ scale,
                                               unsigned short* __restrict__ qb,
                                               unsigned short* __restrict__ kb,
                                               unsigned short* __restrict__ vtb,
                                               unsigned short* __restrict__ vfb){
  __shared__ alignas(16) unsigned short A_[32*168];  // 10752 B
  __shared__ alignas(16) unsigned short VT[64*36];   //  4608 B
  int tid = threadIdx.x;
  int w = tid>>6, lane = tid&63, quad = lane>>4, l16 = lane&15;
  int t0 = blockIdx.x*32;
  float sc2 = scale[0] * 1.44269504089f;

  // LN1: 8 threads per token, x held in registers
  {
    int g = tid>>3, e = tid&7;
    const float* xr = x + (size_t)(t0+g)*147;
    float xv[19];
    float s = 0.f, sq = 0.f;
    #pragma unroll
    for(int i=0;i<19;i++){
      int col = e + 8*i;
      float v = (col < 147) ? xr[col] : 0.f;
      xv[i] = v; s += v; sq += v*v;
    }
    s  += __shfl_xor(s,1,64);  s  += __shfl_xor(s,2,64);  s  += __shfl_xor(s,4,64);
    sq += __shfl_xor(sq,1,64); sq += __shfl_xor(sq,2,64); sq += __shfl_xor(sq,4,64);
    float mean = s*(1.f/147.f);
    float var  = sq*(1.f/147.f) - mean*mean;
    float rstd = rsqrtf(var + 1e-5f);
    #pragma unroll
    for(int i=0;i<19;i++){
      int col = e + 8*i;
      if(col < 147) A_[g*168 + col] = f2b((xv[i]-mean)*rstd*w1[col] + b1[col]);
    }
    #pragma unroll
    for(int i=0;i<2;i++){
      int col = 144 + e + 8*i;
      if(col >= 147 && col < 160) A_[g*168 + col] = 0;
    }
  }
  __syncthreads();
  int mh = (w&1)*16, cb = (w>>1)*96;
  short8 Af[5];
  #pragma unroll
  for(int kk=0;kk<5;kk++)
    Af[kk] = *(const short8*)(A_ + (mh+l16)*168 + kk*32 + quad*8);
  f32x4 acc[6];
  #pragma unroll
  for(int i=0;i<6;i++) acc[i] = (f32x4){0.f,0.f,0.f,0.f};
  #pragma unroll
  for(int nt=0;nt<6;nt++){
    #pragma unroll
    for(int kk=0;kk<5;kk++){
      short8 Bf = *(const short8*)(wp + (size_t)(cb+nt*16+l16)*160 + kk*32 + quad*8);
      acc[nt] = __builtin_amdgcn_mfma_f32_16x16x32_bf16(Af[kk], Bf, acc[nt], 0,0,0);
    }
  }
  #pragma unroll
  for(int nt=0;nt<6;nt++){
    int o = cb + nt*16 + l16;
    #pragma unroll
    for(int r=0;r<4;r++){
      int tl = mh + quad*4 + r;
      int mg = t0 + tl;
      float val = acc[nt][r];
      if(o < 64){
        qb[(size_t)mg*64 + o] = f2b(val*sc2);
      } else if(o < 128){
        kb[(size_t)mg*64 + (o-64)] = f2b(val);
      } else {
        int hd = o - 128;
        unsigned short vb = f2b(val);
        vfb[(size_t)mg*64 + hd] = vb;
        VT[hd*36 + tl] = vb;
      }
    }
  }
  __syncthreads();
  {
    int b = t0 / N_, n0 = t0 - b*N_;
    const unsigned int* VT32 = (const unsigned int*)VT;
    unsigned int* vg = (unsigned int*)vtb + ((size_t)b*64)*(N_/2) + (n0>>1);
    for(int rep=0;rep<4;rep++){
      int f = rep*256 + tid;
      int row = f>>4, c = f&15;
      vg[(size_t)row*(N_/2) + c] = VT32[row*18 + c];
    }
  }
}

// ---------------------------------------------------------------- K2: attention (S^T, async-LDS staging, XOR swizzle)
// grid (98,4,8), 128 thr (2 waves x 16 q = 32 q-rows/block). Extra parallelism from the Q
// dimension (costs no workspace — ws_size caps Op at 4 splits; R6's 8-way overran d_ws).
__global__ __launch_bounds__(128,4) void k_attn(const unsigned short* __restrict__ qb,
                                                const unsigned short* __restrict__ kb,
                                                const unsigned short* __restrict__ vtb,
                                                unsigned short* __restrict__ Opart,
                                                float* __restrict__ lpart){
  __shared__ alignas(16) unsigned int L[4096];   // Ks[2048] | Vs[2048] = 16 KB
  unsigned int* Ks = L;
  unsigned int* Vs = L + 2048;
  int tid = threadIdx.x;
  int w = tid>>6, lane = tid&63, quad = lane>>4, l16 = lane&15;
  int qw = blockIdx.x, sp = blockIdx.y, b = blockIdx.z;
  int q0 = qw*32;
  int qt = qw>>1;                                  // 64-wide kv tile containing the diagonal
  int kv0 = (sp*49)>>2, kv1 = ((sp+1)*49)>>2;

  // Q fragments straight from global (L2-hot): wave w covers q rows q0+w*16 .. +15
  short8 Qf[2];
  {
    const unsigned short* qg = qb + ((size_t)b*N_ + q0 + w*16)*64;
    #pragma unroll
    for(int kk=0;kk<2;kk++)
      Qf[kk] = *(const short8*)(qg + l16*64 + kk*32 + quad*8);
  }
  // per-lane staging byte offsets (kvt-invariant). Lane covers (p = wave row base + lane>>3, cl = lane&7).
  int koffL[4], voffL[4];
  {
    int pl = lane>>3, cl = lane&7;
    #pragma unroll
    for(int rr=0;rr<4;rr++){
      int p = w*32 + rr*8 + pl;
      int sig = (p&32)|((p&12)<<1)|((p&16)>>2)|(p&3);   // K row permutation
      int cx = cl ^ (p&7);                               // XOR col swizzle
      koffL[rr] = sig*128 + cx*16;
      voffL[rr] = p*(N_*2) + cx*16;
    }
  }
  const char* kBase = (const char*)kb + (size_t)b*N_*128;
  const char* vBase = (const char*)vtb + (size_t)b*64*(size_t)(N_*2);

  f32x4 O[4];
  #pragma unroll
  for(int j=0;j<4;j++) O[j] = (f32x4){0.f,0.f,0.f,0.f};
  float lr = 0.f;
  const unsigned short* Ksh = (const unsigned short*)Ks;
  const unsigned short* Vsh = (const unsigned short*)Vs;
  // fragment read sub-offsets (shorts): logical unit (kk*4+quad) ^ (row&7), row&7 == l16&7
  int r7 = l16&7;
  int ku0 = (quad ^ r7)*8;
  int ku1 = ((4+quad) ^ r7)*8;
  int dl = (qw&1)*32 + w*16 + l16;                 // q offset within the diagonal kv tile

  for(int kvt=kv0; kvt<kv1; ++kvt){
    __syncthreads();                               // prev readers done with Ks/Vs
    {
      const char* kT = kBase + (size_t)kvt*8192;
      const char* vT = vBase + (size_t)kvt*128;
      #pragma unroll
      for(int rr=0;rr<4;rr++){
        GLD16(kT + koffL[rr], (char*)Ks + (w*32+rr*8)*128);
        GLD16(vT + voffL[rr], (char*)Vs + (w*32+rr*8)*128);
      }
    }
    __syncthreads();                               // drains vmcnt -> LDS visible

    // S^T = K(perm) . Q^T   (64 kv x 16 q per wave)
    f32x4 S[4];
    #pragma unroll
    for(int jt=0;jt<4;jt++){
      short8 Kf0 = *(const short8*)(Ksh + jt*1024 + l16*64 + ku0);
      short8 Kf1 = *(const short8*)(Ksh + jt*1024 + l16*64 + ku1);
      f32x4 z = (f32x4){0.f,0.f,0.f,0.f};
      S[jt] = __builtin_amdgcn_mfma_f32_16x16x32_bf16(Kf0, Qf[0], z, 0,0,0);
      S[jt] = __builtin_amdgcn_mfma_f32_16x16x32_bf16(Kf1, Qf[1], S[jt], 0,0,0);
    }
    // p = 2^S (fixed-max); lane's S[jt][r] is kv = (jt>>1)*32 + (jt&1)*4 + quad*8 + r
    float p[4][4];
    if(kvt == qt){                                 // diagonal tile (block-uniform branch)
      #pragma unroll
      for(int jt=0;jt<4;jt++){
        int kvb = (jt>>1)*32 + (jt&1)*4 + quad*8;
        #pragma unroll
        for(int r=0;r<4;r++){
          float pv = (kvb + r == dl) ? 0.f : __builtin_amdgcn_exp2f(S[jt][r]);
          p[jt][r] = pv; lr += pv;
        }
      }
    } else {
      #pragma unroll
      for(int jt=0;jt<4;jt++)
        #pragma unroll
        for(int r=0;r<4;r++){
          float pv = __builtin_amdgcn_exp2f(S[jt][r]);
          p[jt][r] = pv; lr += pv;
        }
    }
    pk8 Pb0, Pb1;
    Pb0.u = (u32x4){ pk2t(p[0][0],p[0][1]), pk2t(p[0][2],p[0][3]),
                     pk2t(p[1][0],p[1][1]), pk2t(p[1][2],p[1][3]) };
    Pb1.u = (u32x4){ pk2t(p[2][0],p[2][1]), pk2t(p[2][2],p[2][3]),
                     pk2t(p[3][0],p[3][1]), pk2t(p[3][2],p[3][3]) };
    // O^T += V^T . P^T
    #pragma unroll
    for(int jt2=0;jt2<4;jt2++){
      short8 Vf0 = *(const short8*)(Vsh + jt2*1024 + l16*64 + ku0);
      short8 Vf1 = *(const short8*)(Vsh + jt2*1024 + l16*64 + ku1);
      O[jt2] = __builtin_amdgcn_mfma_f32_16x16x32_bf16(Vf0, Pb0.s, O[jt2], 0,0,0);
      O[jt2] = __builtin_amdgcn_mfma_f32_16x16x32_bf16(Vf1, Pb1.s, O[jt2], 0,0,0);
    }
  }
  // epilogue: reduce l across quads; bounce O^T -> [q][hd] bf16 in LDS; coalesced store
  lr += __shfl_xor(lr,16,64); lr += __shfl_xor(lr,32,64);
  __syncthreads();                                 // all waves done with Ks/Vs
  {
    int q = w*16 + l16;
    #pragma unroll
    for(int jt2=0;jt2<4;jt2++){
      L[q*36 + jt2*8 + quad*2]     = pk2(O[jt2][0], O[jt2][1]);
      L[q*36 + jt2*8 + quad*2 + 1] = pk2(O[jt2][2], O[jt2][3]);
    }
  }
  if(quad == 0){
    size_t lbase = (size_t)sp*TOK_ + (size_t)b*N_ + q0 + w*16;
    lpart[lbase + l16] = lr;
  }
  __syncthreads();
  {
    unsigned int* og = (unsigned int*)(Opart + ((size_t)sp*TOK_ + (size_t)b*N_ + q0)*64);
    #pragma unroll
    for(int rep=0;rep<2;rep++){
      int f = rep*128 + tid;            // 256 x4-units = 32 rows x 8
      int row = f>>3, c = f&7;
      *(u32x4*)(og + row*32 + c*4) = *(const u32x4*)&L[row*36 + c*4];
    }
  }
}

// ---------------------------------------------------------------- K3: merge + proj + residual(v) + LN2 + MLP + residual
__global__ __launch_bounds__(128) void k_mlp(const unsigned short* __restrict__ Opart,
                                             const float* __restrict__ lpart,
                                             const unsigned short* __restrict__ vfb,
                                             const unsigned short* __restrict__ wpj,
                                             const unsigned short* __restrict__ w1b,
                                             const unsigned short* __restrict__ w2b,
                                             const float* __restrict__ projb,
                                             const float* __restrict__ n2w,
                                             const float* __restrict__ n2b,
                                             const float* __restrict__ fc1b,
                                             const float* __restrict__ fc2b,
                                             float* __restrict__ out){
  __shared__ alignas(16) unsigned short Xs[32*72];   // 4608 B
  unsigned int* Xs32 = (unsigned int*)Xs;
  int tid = threadIdx.x;
  int w = tid>>6, lane = tid&63, quad = lane>>4, l16 = lane&15;
  int t0 = blockIdx.x*32;

  // merge NSPLIT KV-split partials (bf16) -> normalized o (bf16) in Xs
  #pragma unroll
  for(int i=0;i<2;i++){
    int f = i*128 + tid;
    int row = f>>3, c = f&7;
    float lo[4] = {0,0,0,0}, hi[4] = {0,0,0,0};
    float lsum = 0.f;
    #pragma unroll
    for(int s=0;s<NSPLIT;s++){
      u32x4 a = *((const u32x4*)(Opart + ((size_t)s*TOK_ + t0)*64) + row*8 + c);
      #pragma unroll
      for(int k=0;k<4;k++){
        lo[k] += __uint_as_float(a[k]<<16);
        hi[k] += __uint_as_float(a[k] & 0xffff0000u);
      }
      lsum += lpart[(size_t)s*TOK_ + t0 + row];
    }
    float linv = 1.f/lsum;
    u32x4 o;
    #pragma unroll
    for(int k=0;k<4;k++) o[k] = pk2(lo[k]*linv, hi[k]*linv);
    *(u32x4*)&Xs32[row*36 + c*4] = o;
  }
  __syncthreads();

  short8 Af[2];
  #pragma unroll
  for(int kk=0;kk<2;kk++)
    Af[kk] = *(const short8*)(Xs + (w*16+l16)*72 + kk*32 + quad*8);
  f32x4 acc[4];
  #pragma unroll
  for(int i=0;i<4;i++) acc[i] = (f32x4){0.f,0.f,0.f,0.f};
  #pragma unroll
  for(int jt=0;jt<4;jt++)
    #pragma unroll
    for(int kk=0;kk<2;kk++){
      short8 Bf = *(const short8*)(wpj + (jt*16+l16)*64 + kk*32 + quad*8);
      acc[jt] = __builtin_amdgcn_mfma_f32_16x16x32_bf16(Af[kk], Bf, acc[jt], 0,0,0);
    }
  float xa[4][4];
  #pragma unroll
  for(int jt=0;jt<4;jt++){
    int col = jt*16 + l16;
    float pb = projb[col];
    #pragma unroll
    for(int r=0;r<4;r++){
      int tg = t0 + w*16 + quad*4 + r;
      xa[jt][r] = acc[jt][r] + pb + b2f(vfb[(size_t)tg*64 + col]);
    }
  }
  #pragma unroll
  for(int r=0;r<4;r++){
    float s = 0.f, sq = 0.f;
    #pragma unroll
    for(int jt=0;jt<4;jt++){ s += xa[jt][r]; sq += xa[jt][r]*xa[jt][r]; }
    s  += __shfl_xor(s,1,64);  s  += __shfl_xor(s,2,64);
    s  += __shfl_xor(s,4,64);  s  += __shfl_xor(s,8,64);
    sq += __shfl_xor(sq,1,64); sq += __shfl_xor(sq,2,64);
    sq += __shfl_xor(sq,4,64); sq += __shfl_xor(sq,8,64);
    float mu = s*(1.f/64.f);
    float var = sq*(1.f/64.f) - mu*mu;
    float rstd = rsqrtf(var + 1e-5f);
    #pragma unroll
    for(int jt=0;jt<4;jt++){
      int col = jt*16 + l16;
      Xs[(w*16+quad*4+r)*72 + col] = f2b((xa[jt][r]-mu)*rstd*n2w[col] + n2b[col]);
    }
  }
  // wave-private rows: no barrier needed
  #pragma unroll
  for(int kk=0;kk<2;kk++)
    Af[kk] = *(const short8*)(Xs + (w*16+l16)*72 + kk*32 + quad*8);
  f32x4 acc2[4];
  #pragma unroll
  for(int i=0;i<4;i++) acc2[i] = (f32x4){0.f,0.f,0.f,0.f};
  #pragma unroll
  for(int jt=0;jt<4;jt++)
    #pragma unroll
    for(int kk=0;kk<2;kk++){
      short8 Bf = *(const short8*)(w1b + (jt*16+l16)*64 + kk*32 + quad*8);
      acc2[jt] = __builtin_amdgcn_mfma_f32_16x16x32_bf16(Af[kk], Bf, acc2[jt], 0,0,0);
    }
  #pragma unroll
  for(int jt=0;jt<4;jt++){
    int col = jt*16 + l16;
    float fb = fc1b[col];
    #pragma unroll
    for(int r=0;r<4;r++){
      float g = acc2[jt][r] + fb;
      float z = g*0.70710678118f;
      float az = fabsf(z);
      float t = 1.f/(1.f + 0.3275911f*az);
      float poly = ((((1.061405429f*t - 1.453152027f)*t + 1.421413741f)*t - 0.284496736f)*t + 0.254829592f)*t;
      float er = 1.f - poly*__builtin_amdgcn_exp2f(-az*az*1.44269504089f);
      er = (z < 0.f) ? -er : er;
      Xs[(w*16+quad*4+r)*72 + col] = f2b(0.5f*g*(1.f + er));
    }
  }
  #pragma unroll
  for(int kk=0;kk<2;kk++)
    Af[kk] = *(const short8*)(Xs + (w*16+l16)*72 + kk*32 + quad*8);
  f32x4 acc3[4];
  #pragma unroll
  for(int i=0;i<4;i++) acc3[i] = (f32x4){0.f,0.f,0.f,0.f};
  #pragma unroll
  for(int jt=0;jt<4;jt++)
    #pragma unroll
    for(int kk=0;kk<2;kk++){
      short8 Bf = *(const short8*)(w2b + (jt*16+l16)*64 + kk*32 + quad*8);
      acc3[jt] = __builtin_amdgcn_mfma_f32_16x16x32_bf16(Af[kk], Bf, acc3[jt], 0,0,0);
    }
  #pragma unroll
  for(int jt=0;jt<4;jt++){
    int col = jt*16 + l16;
    float ob2 = fc2b[col];
    #pragma unroll
    for(int r=0;r<4;r++){
      int tg = t0 + w*16 + quad*4 + r;
      out[(size_t)tg*64 + col] = xa[jt][r] + acc3[jt][r] + ob2;
    }
  }
}

// ---------------------------------------------------------------- launch
extern "C" void kernel_launch(void* const* d_in, const int* in_sizes, int n_in,
                              void* d_out, int out_size, void* d_ws, size_t ws_size,
                              hipStream_t stream){
  const float* x     = (const float*)d_in[0];
  const float* n1w   = (const float*)d_in[1];
  const float* n1b   = (const float*)d_in[2];
  const float* qkvw  = (const float*)d_in[3];
  const float* scale = (const float*)d_in[4];
  const float* projw = (const float*)d_in[5];
  const float* projb = (const float*)d_in[6];
  const float* n2w   = (const float*)d_in[7];
  const float* n2b   = (const float*)d_in[8];
  const float* fc1w  = (const float*)d_in[9];
  const float* fc1b  = (const float*)d_in[10];
  const float* fc2w  = (const float*)d_in[11];
  const float* fc2b  = (const float*)d_in[12];

  char* base = (char*)d_ws;
  unsigned short* wp  = (unsigned short*)(base + 0);          //    61440
  unsigned short* wpj = (unsigned short*)(base + 61440);      //     8192
  unsigned short* w1b = (unsigned short*)(base + 69632);      //     8192
  unsigned short* w2b = (unsigned short*)(base + 77824);      //     8192
  unsigned short* qb  = (unsigned short*)(base + 86016);      //  3211264
  unsigned short* kb  = (unsigned short*)(base + 3297280);    //  3211264
  unsigned short* vtb = (unsigned short*)(base + 6508544);    //  3211264
  unsigned short* vfb = (unsigned short*)(base + 9719808);    //  3211264
  unsigned short* Op  = (unsigned short*)(base + 12931072);   // 12845056 (4 splits bf16)
  float*          lp  = (float*)(base + 25776128);            //   401408  -> total 26177536

  hipLaunchKernelGGL(k_prep, dim3(120),      dim3(256), 0, stream,
                     qkvw, projw, fc1w, fc2w, wp, wpj, w1b, w2b);
  hipLaunchKernelGGL(k_qkv,  dim3(TOK_/32),  dim3(256), 0, stream,
                     x, n1w, n1b, wp, scale, qb, kb, vtb, vfb);
  hipLaunchKernelGGL(k_attn, dim3(98,NSPLIT,8), dim3(128), 0, stream, qb, kb, vtb, Op, lp);
  hipLaunchKernelGGL(k_mlp,  dim3(TOK_/32),  dim3(128), 0, stream, Op, lp, vfb,
                     wpj, w1b, w2b, projb, n2w, n2b, fc1b, fc2b, (float*)d_out);
}